// Round 8
// baseline (415.171 us; speedup 1.0000x reference)
//
#include <hip/hip_runtime.h>
#include <math.h>

#define BATCH 4
#define SLEN 2048
#define DMODEL 1024
#define NH 16
#define HD 64
#define MROWS (BATCH * SLEN)  // 8192
#define QK_LD 2048            // fused Q|K row stride

typedef __attribute__((ext_vector_type(8))) short short8;
typedef __attribute__((ext_vector_type(4))) float floatx4;

#define AS1 __attribute__((address_space(1)))
#define AS3 __attribute__((address_space(3)))

__device__ inline unsigned short f2bf(float f) {
    union { float f; unsigned u; } a; a.f = f;
    unsigned r = a.u + 0x7fff + ((a.u >> 16) & 1);  // RNE
    return (unsigned short)(r >> 16);
}

// pack two fp32 -> bf16x2, round-half-up (epilogue use)
__device__ inline unsigned pack_bf(float lo, float hi) {
    union { float f; unsigned u; } a, b; a.f = lo; b.f = hi;
    return __builtin_amdgcn_perm(b.u + 0x8000u, a.u + 0x8000u, 0x07060302u);
}
// pack two fp32 -> bf16x2, truncation (P matrix: bias cancels in P/lsum)
__device__ inline unsigned pack_tr(float lo, float hi) {
    union { float f; unsigned u; } a, b; a.f = lo; b.f = hi;
    return __builtin_amdgcn_perm(b.u, a.u, 0x07060302u);
}

// ---------------- conversion kernels ----------------

__global__ __launch_bounds__(256) void cvt_bf16(const float* __restrict__ src,
                                                short* __restrict__ dst) {
    int i = (blockIdx.x * 256 + threadIdx.x) * 4;
    float4 v = *(const float4*)(src + i);
    unsigned short t0 = f2bf(v.x), t1 = f2bf(v.y), t2 = f2bf(v.z), t3 = f2bf(v.w);
    uint2 o;
    o.x = (unsigned)t0 | ((unsigned)t1 << 16);
    o.y = (unsigned)t2 | ((unsigned)t3 << 16);
    *(uint2*)(dst + i) = o;
}

// all four weight transposes in one launch; Wq pre-scaled by 0.125*log2(e)
__global__ __launch_bounds__(256) void cvt_wT4(
    const float* __restrict__ Wq, const float* __restrict__ Wk,
    const float* __restrict__ Wv, const float* __restrict__ Wo,
    short* __restrict__ WqkT, short* __restrict__ WvT, short* __restrict__ WoT)
{
    const float* W; short* Wt; float sc = 1.0f;
    int z = blockIdx.z;
    if (z == 0)      { W = Wq; Wt = WqkT; sc = 0.18033688011112042f; }
    else if (z == 1) { W = Wk; Wt = WqkT + (size_t)DMODEL * DMODEL; }
    else if (z == 2) { W = Wv; Wt = WvT; }
    else             { W = Wo; Wt = WoT; }

    __shared__ float t[32][33];
    int bn = blockIdx.x * 32, bk = blockIdx.y * 32;
    int tx = threadIdx.x & 31, r0 = (threadIdx.x >> 5) * 4;
    #pragma unroll
    for (int i = 0; i < 4; i++)
        t[r0 + i][tx] = W[(size_t)(bk + r0 + i) * DMODEL + bn + tx];
    __syncthreads();
    #pragma unroll
    for (int i = 0; i < 4; i++)
        Wt[(size_t)(bn + r0 + i) * DMODEL + bk + tx] = (short)f2bf(t[tx][r0 + i] * sc);
}

// ---------------- MFMA GEMM (m97 recipe) ----------------
#define TM 128
#define TN 128
#define TK 32

template <int OUT_BF16>
__global__ __launch_bounds__(256) void mfma_gemm(
    const short* __restrict__ A,    // bf16 [M][K]
    const short* __restrict__ Bt,   // bf16 [N][K]
    const float* __restrict__ bias,
    void* __restrict__ Cout, int M, int N, int K)
{
    __shared__ short As[TM * TK];
    __shared__ short Bs[TN * TK];
    int tid = threadIdx.x;
    int m0 = blockIdx.y * TM, n0 = blockIdx.x * TN;
    int l = tid & 63, w = tid >> 6;
    int wm = (w >> 1) * 64, wn = (w & 1) * 64;
    int lr = l & 15, lk = (l >> 4) * 8;

    floatx4 acc[4][4] = {};

    for (int k0 = 0; k0 < K; k0 += TK) {
        #pragma unroll
        for (int r = 0; r < 2; r++) {
            int c = r * 256 + tid;
            int mm = c >> 2, kk = (c & 3) * 8;
            __builtin_amdgcn_global_load_lds(
                (const AS1 void*)(A + (size_t)(m0 + mm) * K + k0 + kk),
                (AS3 void*)(As + c * 8), 16, 0, 0);
            __builtin_amdgcn_global_load_lds(
                (const AS1 void*)(Bt + (size_t)(n0 + mm) * K + k0 + kk),
                (AS3 void*)(Bs + c * 8), 16, 0, 0);
        }
        __syncthreads();

        short8 af[4], bg[4];
        #pragma unroll
        for (int i = 0; i < 4; i++) {
            af[i] = *(const short8*)(As + (wm + i * 16 + lr) * TK + lk);
            bg[i] = *(const short8*)(Bs + (wn + i * 16 + lr) * TK + lk);
        }
        #pragma unroll
        for (int mi = 0; mi < 4; mi++)
            #pragma unroll
            for (int ni = 0; ni < 4; ni++)
                acc[mi][ni] = __builtin_amdgcn_mfma_f32_16x16x32_bf16(
                    af[mi], bg[ni], acc[mi][ni], 0, 0, 0);
        __syncthreads();
    }

    int rbase = (l >> 4) * 4, cbase = l & 15;
    if (OUT_BF16) {
        short* C = (short*)Cout;
        #pragma unroll
        for (int mi = 0; mi < 4; mi++)
            #pragma unroll
            for (int r = 0; r < 4; r++) {
                int row = m0 + wm + mi * 16 + rbase + r;
                #pragma unroll
                for (int ni = 0; ni < 4; ni++) {
                    int col = n0 + wn + ni * 16 + cbase;
                    C[(size_t)row * N + col] = (short)f2bf(acc[mi][ni][r]);
                }
            }
    } else {
        float* C = (float*)Cout;
        #pragma unroll
        for (int mi = 0; mi < 4; mi++)
            #pragma unroll
            for (int r = 0; r < 4; r++) {
                int row = m0 + wm + mi * 16 + rbase + r;
                #pragma unroll
                for (int ni = 0; ni < 4; ni++) {
                    int col = n0 + wn + ni * 16 + cbase;
                    C[(size_t)row * N + col] = acc[mi][ni][r] + bias[col];
                }
            }
    }
}

// ---------------- MFMA flash attention, pair-merged kt sweep ----------------
// S^T = K Q'^T (Q' pre-scaled by 0.125*log2e -> p = exp2(s), no-max softmax).
// Each block owns q-tiles A=31-p (long) and B=p (short) and runs ONE kt sweep
// 0..31-p; tile B is active for kt<=p. K/V fragments are read once per kt and
// feed both tiles' MFMAs (halves wave-redundant LDS reads in the overlap).
// lsum on the MFMA pipe via ones-fragment. Grid (bh, p): XCD-local K/V reuse.
#define PSTR 72  // Ps row stride in shorts

__global__ __launch_bounds__(256, 4) void fa_mfma(
    const short* __restrict__ QK, const short* __restrict__ VtT,
    short* __restrict__ ctx)
{
    __shared__ __align__(16) short Ks[2][64][32];    // [d-half][kv][d%32] (qtr-swizzled)
    __shared__ __align__(16) short Vs[2][64][32];    // [kv-half][d][kv%32] (qtr-swizzled)
    __shared__ __align__(16) short PsA[4][16][PSTR]; // [wave][q][kv]
    __shared__ __align__(16) short PsB[4][16][PSTR];

    int tid = threadIdx.x;
    int l = tid & 63, w = tid >> 6;
    int lr = l & 15, lg = l >> 4;
    int bh = blockIdx.x;               // XCD-locality: same bh -> same XCD
    int b = bh >> 4, h = bh & 15;
    int p = blockIdx.y;                // 0..15

    const short* Qbase = QK + (size_t)b * SLEN * QK_LD + h * HD;
    const short* Kbase = Qbase + 1024;
    const short* Vbase = VtT + (size_t)h * HD * MROWS + b * SLEN;

    int xoff = (lg ^ ((lr >> 1) & 3)) * 8;  // swizzled quarter for frag reads

    short8 ones;
    #pragma unroll
    for (int j = 0; j < 8; j++) ones[j] = (short)0x3F80;  // bf16 1.0

    int qtA = 31 - p, qtB = p;
    int qrowA = qtA * 64 + w * 16 + lr;
    int qrowB = qtB * 64 + w * 16 + lr;

    short8 qfA[2], qfB[2];
    #pragma unroll
    for (int kk = 0; kk < 2; kk++) {
        qfA[kk] = *(const short8*)(Qbase + (size_t)qrowA * QK_LD + kk * 32 + lg * 8);
        qfB[kk] = *(const short8*)(Qbase + (size_t)qrowB * QK_LD + kk * 32 + lg * 8);
    }

    floatx4 OA[4] = {}, OB[4] = {};
    floatx4 accLA = {}, accLB = {};

    for (int kt = 0; kt <= qtA; kt++) {
        int k0 = kt * 64;
        bool actB = (kt <= qtB);  // block-uniform
        __syncthreads();  // WAR on Ks/Vs
        #pragma unroll
        for (int r2 = 0; r2 < 2; r2++) {
            int c = r2 * 256 + tid;
            int kh = c >> 8, rr = (c >> 2) & 63;
            int q = (c & 3) ^ ((rr >> 1) & 3);
            __builtin_amdgcn_global_load_lds(
                (const AS1 void*)(Kbase + (size_t)(k0 + rr) * QK_LD + kh * 32 + q * 8),
                (AS3 void*)(&Ks[0][0][0] + c * 8), 16, 0, 0);
            __builtin_amdgcn_global_load_lds(
                (const AS1 void*)(Vbase + (size_t)rr * MROWS + k0 + kh * 32 + q * 8),
                (AS3 void*)(&Vs[0][0][0] + c * 8), 16, 0, 0);
        }
        __syncthreads();

        // S^T = K Q'^T for both tiles; kf read once, used twice
        floatx4 sA[4] = {}, sB[4] = {};
        #pragma unroll
        for (int kk = 0; kk < 2; kk++)
            #pragma unroll
            for (int t = 0; t < 4; t++) {
                short8 kf = *(const short8*)(&Ks[kk][t * 16 + lr][xoff]);
                sA[t] = __builtin_amdgcn_mfma_f32_16x16x32_bf16(kf, qfA[kk], sA[t], 0, 0, 0);
                if (actB)
                    sB[t] = __builtin_amdgcn_mfma_f32_16x16x32_bf16(kf, qfB[kk], sB[t], 0, 0, 0);
            }

        // tile A: mask (diagonal only), exp2, pack -> PsA
        if (kt == qtA) {
            #pragma unroll
            for (int t = 0; t < 4; t++)
                #pragma unroll
                for (int r = 0; r < 4; r++)
                    if (k0 + t * 16 + lg * 4 + r > qrowA) sA[t][r] = -INFINITY;
        }
        #pragma unroll
        for (int t = 0; t < 4; t++) {
            float p0 = __builtin_amdgcn_exp2f(sA[t][0]);
            float p1 = __builtin_amdgcn_exp2f(sA[t][1]);
            float p2 = __builtin_amdgcn_exp2f(sA[t][2]);
            float p3 = __builtin_amdgcn_exp2f(sA[t][3]);
            uint2 pk;
            pk.x = pack_tr(p0, p1);
            pk.y = pack_tr(p2, p3);
            *(uint2*)(&PsA[w][lr][t * 16 + lg * 4]) = pk;
        }
        if (actB) {
            if (kt == qtB) {
                #pragma unroll
                for (int t = 0; t < 4; t++)
                    #pragma unroll
                    for (int r = 0; r < 4; r++)
                        if (k0 + t * 16 + lg * 4 + r > qrowB) sB[t][r] = -INFINITY;
            }
            #pragma unroll
            for (int t = 0; t < 4; t++) {
                float p0 = __builtin_amdgcn_exp2f(sB[t][0]);
                float p1 = __builtin_amdgcn_exp2f(sB[t][1]);
                float p2 = __builtin_amdgcn_exp2f(sB[t][2]);
                float p3 = __builtin_amdgcn_exp2f(sB[t][3]);
                uint2 pk;
                pk.x = pack_tr(p0, p1);
                pk.y = pack_tr(p2, p3);
                *(uint2*)(&PsB[w][lr][t * 16 + lg * 4]) = pk;
            }
        }

        // PV for both tiles; vf read once, used twice
        #pragma unroll
        for (int kk = 0; kk < 2; kk++) {
            short8 pfA = *(const short8*)(&PsA[w][lr][kk * 32 + lg * 8]);
            accLA = __builtin_amdgcn_mfma_f32_16x16x32_bf16(ones, pfA, accLA, 0, 0, 0);
            short8 pfB;
            if (actB) {
                pfB = *(const short8*)(&PsB[w][lr][kk * 32 + lg * 8]);
                accLB = __builtin_amdgcn_mfma_f32_16x16x32_bf16(ones, pfB, accLB, 0, 0, 0);
            }
            #pragma unroll
            for (int dt = 0; dt < 4; dt++) {
                short8 vf = *(const short8*)(&Vs[kk][dt * 16 + lr][xoff]);
                OA[dt] = __builtin_amdgcn_mfma_f32_16x16x32_bf16(vf, pfA, OA[dt], 0, 0, 0);
                if (actB)
                    OB[dt] = __builtin_amdgcn_mfma_f32_16x16x32_bf16(vf, pfB, OB[dt], 0, 0, 0);
            }
        }
    }

    // epilogues
    {
        float linv = 1.f / accLA[0];
        short* crow = ctx + ((size_t)b * SLEN + qrowA) * DMODEL + h * HD;
        #pragma unroll
        for (int dt = 0; dt < 4; dt++) {
            uint2 pk;
            pk.x = pack_bf(OA[dt][0] * linv, OA[dt][1] * linv);
            pk.y = pack_bf(OA[dt][2] * linv, OA[dt][3] * linv);
            *(uint2*)(crow + dt * 16 + lg * 4) = pk;
        }
    }
    {
        float linv = 1.f / accLB[0];
        short* crow = ctx + ((size_t)b * SLEN + qrowB) * DMODEL + h * HD;
        #pragma unroll
        for (int dt = 0; dt < 4; dt++) {
            uint2 pk;
            pk.x = pack_bf(OB[dt][0] * linv, OB[dt][1] * linv);
            pk.y = pack_bf(OB[dt][2] * linv, OB[dt][3] * linv);
            *(uint2*)(crow + dt * 16 + lg * 4) = pk;
        }
    }
}

// ---------------- launcher ----------------
extern "C" void kernel_launch(void* const* d_in, const int* in_sizes, int n_in,
                              void* d_out, int out_size, void* d_ws, size_t ws_size,
                              hipStream_t stream) {
    const float* x  = (const float*)d_in[0];
    const float* Wq = (const float*)d_in[1];
    const float* Wk = (const float*)d_in[2];
    const float* Wv = (const float*)d_in[3];
    const float* Wo = (const float*)d_in[4];
    const float* bo = (const float*)d_in[5];
    float* out = (float*)d_out;

    const size_t tsz = (size_t)MROWS * DMODEL;  // 8.4M
    const size_t wsz = (size_t)DMODEL * DMODEL; // 1M

    short* xb    = (short*)d_ws;        // [8192][1024]
    short* WqkT  = xb + tsz;            // [2048][1024]  (WqT | WkT stacked)
    short* WvT   = WqkT + 2 * wsz;      // [1024][1024]
    short* WoT   = WvT + wsz;           // [1024][1024]
    short* QKb   = WoT + wsz;           // [8192][2048]
    short* VtT   = QKb + 2 * tsz;       // [1024][8192]  V transposed
    short* Cb    = VtT + tsz;           // [8192][1024]  ctx

    cvt_bf16<<<(int)(tsz / (256 * 4)), 256, 0, stream>>>(x, xb);
    cvt_wT4<<<dim3(32, 32, 4), 256, 0, stream>>>(Wq, Wk, Wv, Wo, WqkT, WvT, WoT);

    // fused Q|K projection: [8192,1024] @ [1024,2048] -> [8192,2048]
    mfma_gemm<1><<<dim3(2048 / TN, MROWS / TM), 256, 0, stream>>>(
        xb, WqkT, nullptr, QKb, MROWS, 2048, DMODEL);
    // V^T directly: WvT[d][k] @ xb[m][k]^T -> VtT[d][m]
    mfma_gemm<1><<<dim3(MROWS / TN, DMODEL / TM), 256, 0, stream>>>(
        WvT, xb, nullptr, VtT, DMODEL, MROWS, DMODEL);

    // grid (bh, p): XCD-local K/V reuse; merged pair sweep per block
    fa_mfma<<<dim3(BATCH * NH, 16), 256, 0, stream>>>(QKb, VtT, Cb);

    mfma_gemm<0><<<dim3(DMODEL / TN, MROWS / TM), 256, 0, stream>>>(
        Cb, WoT, bo, out, MROWS, DMODEL, DMODEL);
}